// Round 4
// baseline (180.998 us; speedup 1.0000x reference)
//
#include <hip/hip_runtime.h>
#include <stdint.h>

// Bert4Argument: out[b,l,c] = sum_f feat[b,l,f] * W[c,f] + b[c]
// feat = [ seq[i, head[i,l], :] | pos_emb[l-pos[i]+256, :] | class_emb[(l==pos[i])?frame[i]:0, :] ]
// B=64, L=256, D=768 -> M=16384, K=2304, N=200 (13 n-tiles of 16)
//
// R4: latency-proof structure. Block = 4 waves / 64 rows. Wave owns n-tiles
// {w, w+4, w+8 (+12 if w==0)} and DMA-stages its own packed-W chunks into
// PRIVATE LDS (global_load_lds, triple-buffered, distance-1 prefetch,
// per-wave exact vmcnt waits, ZERO barriers). Each wave computes all 4
// m-frags x its tiles -> each B fragment feeds 4 MFMAs. A read as f32
// directly from global (no seq mirror), whole chunk loaded before the
// vmcnt wait so its latency hides behind the DMA drain.

typedef __attribute__((ext_vector_type(8))) short short8;
typedef __attribute__((ext_vector_type(4))) float f32x4;

#define AS1 __attribute__((address_space(1)))
#define AS3 __attribute__((address_space(3)))

#define NW_G 59904                       // 13*288*16 pack work-items
#define WP_NEED ((size_t)479232 * 2)     // 958,464 B packed W

__device__ __forceinline__ unsigned short f2bf(float f) {
    union { float f; unsigned int u; } v; v.f = f;
    unsigned int u = v.u;
    return (unsigned short)((u + 0x7fffu + ((u >> 16) & 1u)) >> 16);
}

__device__ __forceinline__ short8 pack8(f32x4 a, f32x4 b) {
    short8 r;
    r[0] = (short)f2bf(a.x); r[1] = (short)f2bf(a.y);
    r[2] = (short)f2bf(a.z); r[3] = (short)f2bf(a.w);
    r[4] = (short)f2bf(b.x); r[5] = (short)f2bf(b.y);
    r[6] = (short)f2bf(b.z); r[7] = (short)f2bf(b.w);
    return r;
}

// ---------------------------------------------------------------------------
// Pack W f32 [200][2304] -> bf16 tiled: Wp[((t*288+kb8)*16+n)*8+j] = W[t*16+n][kb8*8+j]
// ---------------------------------------------------------------------------
__global__ void cvt_w_kernel(const float* __restrict__ W,
                             unsigned short* __restrict__ Wp) {
    int u = blockIdx.x * 256 + threadIdx.x;
    if (u >= NW_G) return;
    int n   = u & 15;
    int kb8 = (u >> 4) % 288;
    int t   = u / (288 * 16);
    int row = t * 16 + n;
    int col = kb8 * 8;
    f32x4 a = {0.f, 0.f, 0.f, 0.f}, b = {0.f, 0.f, 0.f, 0.f};
    if (row < 200) {
        const float* p = W + (size_t)row * 2304 + col;
        a = *(const f32x4*)p;
        b = *(const f32x4*)(p + 4);
    }
    *(short8*)(Wp + (size_t)u * 8) = pack8(a, b);
}

__device__ __forceinline__ void dma16(const unsigned short* g, AS3 unsigned short* l) {
    __builtin_amdgcn_global_load_lds((AS1 const unsigned int*)g,
                                     (AS3 unsigned int*)l, 16, 0, 0);
}

// ---------------------------------------------------------------------------
// GEMM: grid 256 blocks x 256 thr. Block b covers rows [64b, 64b+64)
// (one batch i = b>>2). LDS: 4 waves x 3 bufs x 4 tile-slots x 2 KB = 96 KB.
// ---------------------------------------------------------------------------
__global__ __launch_bounds__(256) void gemm3_kernel(
    const float* __restrict__ seq,   // [64,256,768]
    const float* __restrict__ pe,    // [513,768]
    const float* __restrict__ ce,    // [201,768]
    const float* __restrict__ bias,  // [200]
    const int*   __restrict__ head,  // [64,256]
    const int*   __restrict__ frame, // [64]
    const int*   __restrict__ pos,   // [64]
    const unsigned short* __restrict__ Wp,  // packed bf16 W
    float* __restrict__ out)         // [16384,200]
{
    __shared__ unsigned short ldsAll[4 * 3 * 4 * 1024];   // 96 KB

    const int tid  = threadIdx.x;
    const int wave = tid >> 6;
    const int lane = tid & 63;
    const int n16  = lane & 15;
    const int quad = lane >> 4;
    const int nt   = (wave == 0) ? 4 : 3;   // owned n-tiles: t = wave + 4u

    const int i       = blockIdx.x >> 2;    // batch (64 rows per block, 256/batch)
    const int pos_i   = pos[i];
    const int frame_i = frame[i];

    // A-operand pointers, per m-frag f (rows blockIdx*64 + f*16 + n16)
    const float* aptr[3][4];
#pragma unroll
    for (int f = 0; f < 4; ++f) {
        const int mrow = blockIdx.x * 64 + f * 16 + n16;
        const int j    = mrow & 255;
        const int hi   = head[mrow];
        const int rel  = j - pos_i + 256;               // [1, 511]
        const int cls  = (j == pos_i) ? frame_i : 0;
        aptr[0][f] = seq + ((size_t)i * 256 + (size_t)hi) * 768 + quad * 8;
        aptr[1][f] = pe + (size_t)rel * 768 + quad * 8;
        aptr[2][f] = ce + (size_t)cls * 768 + quad * 8;
    }

    f32x4 acc[4][4];   // [m-frag][tile-slot]
#pragma unroll
    for (int u = 0; u < 4; ++u) {
        const int t = wave + 4 * u;
        const int col = t * 16 + n16;
        const float bv = (t < 13 && col < 200) ? bias[col] : 0.0f;
#pragma unroll
        for (int f = 0; f < 4; ++f) acc[f][u] = (f32x4){bv, bv, bv, bv};
    }

    // LDS bases
    const unsigned short* lbase = ldsAll + wave * 12288;           // generic (reads)
    AS3 unsigned short* lw = (AS3 unsigned short*)ldsAll + wave * 12288; // DMA dest

    // stage chunk c (64 k-values, 8 kb8-blocks) into buffer b
    auto stage = [&](int c, int b) {
#pragma unroll
        for (int u = 0; u < 4; ++u) {
            if (u < nt) {
                const int t = wave + 4 * u;
                const unsigned short* s =
                    Wp + (((size_t)t * 288 + (size_t)c * 8) << 7) + lane * 8;
                dma16(s,       lw + b * 4096 + u * 1024);
                dma16(s + 512, lw + b * 4096 + u * 1024 + 512);
            }
        }
    };

    stage(0, 0);   // prologue: chunk 0 -> buf 0

#pragma unroll
    for (int sg = 0; sg < 3; ++sg) {
        const float* ap0 = aptr[sg][0];
        const float* ap1 = aptr[sg][1];
        const float* ap2 = aptr[sg][2];
        const float* ap3 = aptr[sg][3];
        int b0 = 0;                       // 12 % 3 == 0 -> consistent across sg
        for (int cc = 0; cc < 12; ++cc) {
            const int c = sg * 12 + cc;
            // A f32 for the whole chunk (both k-steps), issued before the wait
            f32x4 av[4][4];
            {
                const float* p0 = ap0 + cc * 64;
                const float* p1 = ap1 + cc * 64;
                const float* p2 = ap2 + cc * 64;
                const float* p3 = ap3 + cc * 64;
                av[0][0] = *(const f32x4*)(p0);      av[0][1] = *(const f32x4*)(p0 + 4);
                av[0][2] = *(const f32x4*)(p0 + 32); av[0][3] = *(const f32x4*)(p0 + 36);
                av[1][0] = *(const f32x4*)(p1);      av[1][1] = *(const f32x4*)(p1 + 4);
                av[1][2] = *(const f32x4*)(p1 + 32); av[1][3] = *(const f32x4*)(p1 + 36);
                av[2][0] = *(const f32x4*)(p2);      av[2][1] = *(const f32x4*)(p2 + 4);
                av[2][2] = *(const f32x4*)(p2 + 32); av[2][3] = *(const f32x4*)(p2 + 36);
                av[3][0] = *(const f32x4*)(p3);      av[3][1] = *(const f32x4*)(p3 + 4);
                av[3][2] = *(const f32x4*)(p3 + 32); av[3][3] = *(const f32x4*)(p3 + 36);
            }
            int b1 = b0 + 1; if (b1 == 3) b1 = 0;
            const bool has_next = (c + 1 < 36);
            if (has_next) stage(c + 1, b1);
            asm volatile("" ::: "memory");
            // Wait for chunk c's DMAs: they are the oldest outstanding VMEM ops;
            // exactly 2*nt ops (chunk c+1's) were issued after them, so
            // vmcnt(2*nt) is safe regardless of where A-loads landed.
            if (has_next) {
                if (wave == 0) __builtin_amdgcn_s_waitcnt(0xF78);  // vmcnt(8)
                else           __builtin_amdgcn_s_waitcnt(0xF76);  // vmcnt(6)
            } else {
                __builtin_amdgcn_s_waitcnt(0xF70);                 // vmcnt(0)
            }
            asm volatile("" ::: "memory");

            const unsigned short* lb = lbase + b0 * 4096;
#pragma unroll
            for (int kc = 0; kc < 2; ++kc) {
                short8 af0 = pack8(av[0][kc * 2], av[0][kc * 2 + 1]);
                short8 af1 = pack8(av[1][kc * 2], av[1][kc * 2 + 1]);
                short8 af2 = pack8(av[2][kc * 2], av[2][kc * 2 + 1]);
                short8 af3 = pack8(av[3][kc * 2], av[3][kc * 2 + 1]);
                const int lo = ((kc * 4 + quad) * 16 + n16) * 8;
#pragma unroll
                for (int u = 0; u < 4; ++u) {
                    if (u < nt) {
                        short8 bf = *(const short8*)(lb + u * 1024 + lo);
                        acc[0][u] = __builtin_amdgcn_mfma_f32_16x16x32_bf16(af0, bf, acc[0][u], 0, 0, 0);
                        acc[1][u] = __builtin_amdgcn_mfma_f32_16x16x32_bf16(af1, bf, acc[1][u], 0, 0, 0);
                        acc[2][u] = __builtin_amdgcn_mfma_f32_16x16x32_bf16(af2, bf, acc[2][u], 0, 0, 0);
                        acc[3][u] = __builtin_amdgcn_mfma_f32_16x16x32_bf16(af3, bf, acc[3][u], 0, 0, 0);
                    }
                }
            }
            b0 = b1;
        }
    }

    // epilogue: C/D layout col = lane&15, row = quad*4 + r (within 16-row frag)
#pragma unroll
    for (int f = 0; f < 4; ++f) {
        const int rbase = blockIdx.x * 64 + f * 16 + quad * 4;
#pragma unroll
        for (int u = 0; u < 4; ++u) {
            const int t = wave + 4 * u;
            if (t < 13) {
                const int col = t * 16 + n16;
                if (col < 200) {
#pragma unroll
                    for (int r = 0; r < 4; ++r)
                        out[(size_t)(rbase + r) * 200 + col] = acc[f][u][r];
                }
            }
        }
    }
}

// ---------------------------------------------------------------------------
// Fallback (no workspace): slow but correct, f32 W converted inline.
// ---------------------------------------------------------------------------
__global__ __launch_bounds__(256) void gemm_fallback(
    const float* __restrict__ seq, const float* __restrict__ pe,
    const float* __restrict__ ce, const float* __restrict__ Wf,
    const float* __restrict__ bias, const int* __restrict__ head,
    const int* __restrict__ frame, const int* __restrict__ pos,
    float* __restrict__ out)
{
    const int tid  = threadIdx.x;
    const int wave = tid >> 6;
    const int lane = tid & 63;
    const int n16  = lane & 15;
    const int quad = lane >> 4;

    const int mrow  = blockIdx.x * 16 + n16;
    const int i     = mrow >> 8;
    const int j     = mrow & 255;
    const int pos_i = pos[i];
    const int hi    = head[mrow];
    const int rel   = j - pos_i + 256;
    const int cls   = (j == pos_i) ? frame[i] : 0;

    const float* segs[3];
    segs[0] = seq + ((size_t)i * 256 + (size_t)hi) * 768 + quad * 8;
    segs[1] = pe + (size_t)rel * 768 + quad * 8;
    segs[2] = ce + (size_t)cls * 768 + quad * 8;

    const int ntl = (wave == 0) ? 4 : 3;
    f32x4 acc[4];
#pragma unroll
    for (int u = 0; u < 4; ++u) {
        const int t = wave + 4 * u;
        const int col = t * 16 + n16;
        const float bv = (t < 13 && col < 200) ? bias[col] : 0.0f;
        acc[u] = (f32x4){bv, bv, bv, bv};
    }

    for (int s = 0; s < 3; ++s) {
        const float* ap = segs[s];
#pragma unroll 2
        for (int kk = 0; kk < 768; kk += 32) {
            short8 afr = pack8(*(const f32x4*)(ap + kk), *(const f32x4*)(ap + kk + 4));
#pragma unroll
            for (int u = 0; u < 4; ++u) {
                if (u < ntl) {
                    const int t = wave + 4 * u;
                    const int row = t * 16 + n16;
                    short8 bfr = {0, 0, 0, 0, 0, 0, 0, 0};
                    if (row < 200) {
                        const float* qp = Wf + (size_t)row * 2304 + s * 768 + kk + quad * 8;
                        bfr = pack8(*(const f32x4*)qp, *(const f32x4*)(qp + 4));
                    }
                    acc[u] = __builtin_amdgcn_mfma_f32_16x16x32_bf16(afr, bfr, acc[u], 0, 0, 0);
                }
            }
        }
    }

    const int rbase = blockIdx.x * 16 + quad * 4;
#pragma unroll
    for (int u = 0; u < 4; ++u) {
        const int t = wave + 4 * u;
        if (t < 13) {
            const int col = t * 16 + n16;
            if (col < 200) {
#pragma unroll
                for (int r = 0; r < 4; ++r)
                    out[(size_t)(rbase + r) * 200 + col] = acc[u][r];
            }
        }
    }
}

// ---------------------------------------------------------------------------
extern "C" void kernel_launch(void* const* d_in, const int* in_sizes, int n_in,
                              void* d_out, int out_size, void* d_ws, size_t ws_size,
                              hipStream_t stream) {
    const float* seq  = (const float*)d_in[0];
    const float* pe   = (const float*)d_in[1];
    const float* ce   = (const float*)d_in[2];
    const float* W    = (const float*)d_in[3];
    const float* bias = (const float*)d_in[4];
    const int* head   = (const int*)d_in[5];
    const int* frame  = (const int*)d_in[6];
    const int* pos    = (const int*)d_in[7];
    float* out = (float*)d_out;

    if (d_ws != nullptr && ws_size >= WP_NEED) {
        unsigned short* Wp = (unsigned short*)d_ws;
        cvt_w_kernel<<<(NW_G + 255) / 256, 256, 0, stream>>>(W, Wp);
        gemm3_kernel<<<256, 256, 0, stream>>>(seq, pe, ce, bias, head, frame,
                                              pos, Wp, out);
    } else {
        gemm_fallback<<<1024, 256, 0, stream>>>(seq, pe, ce, W, bias, head,
                                                frame, pos, out);
    }
}

// Round 5
// 160.972 us; speedup vs baseline: 1.1244x; 1.1244x over previous
//
#include <hip/hip_runtime.h>
#include <stdint.h>

// Bert4Argument: out[b,l,c] = sum_f feat[b,l,f] * W[c,f] + b[c]
// feat = [ seq[i, head[i,l], :] | pos_emb[l-pos[i]+256, :] | class_emb[(l==pos[i])?frame[i]:0, :] ]
// B=64, L=256, D=768 -> M=16384, K=2304, N=200 (padded to 16 tiles of 16 = 256)
//
// R5: branchless, register-pipelined K-loop.
//  - prep: bf16 mirrors of seq/pe/ce + packed W padded to 16 n-tiles (zeros).
//  - gemm: 256 blocks x 512 thr (8 waves). wave: p=w&1 -> m-frags {2p,2p+1},
//    q=w>>1 -> tiles {q,q+4,q+8,q+12}. acc[2][4].
//  - inner loop fully unrolled, 3 rotating fragment buffers, prefetch
//    distance 2, compile-time clamped at segment end -> ZERO branches, loads
//    always ~2 iters ahead of their MFMAs.

typedef __attribute__((ext_vector_type(8))) short short8;
typedef __attribute__((ext_vector_type(4))) float f32x4;

#define NSEQ_G 1572864   // 64*256*768/8
#define NPE_G  49248     // 513*768/8
#define NCE_G  19296     // 201*768/8
#define NW16_G 73728     // 16*288*16
#define SEQB_OFF 0
#define PEB_OFF  12582912
#define CEB_OFF  (PEB_OFF + 393984)     // 12,976,896
#define WP_OFF   (CEB_OFF + 154368)     // 13,131,264
#define WS_ELEMS (WP_OFF + 589824)      // 13,721,088
#define WS_NEED  ((size_t)WS_ELEMS * 2) // 27,442,176 B
#define TILE_STRIDE 36864               // 288*16*8 elems per n-tile

__device__ __forceinline__ unsigned short f2bf(float f) {
    union { float f; unsigned int u; } v; v.f = f;
    unsigned int u = v.u;
    return (unsigned short)((u + 0x7fffu + ((u >> 16) & 1u)) >> 16);
}

__device__ __forceinline__ short8 pack8(f32x4 a, f32x4 b) {
    short8 r;
    r[0] = (short)f2bf(a.x); r[1] = (short)f2bf(a.y);
    r[2] = (short)f2bf(a.z); r[3] = (short)f2bf(a.w);
    r[4] = (short)f2bf(b.x); r[5] = (short)f2bf(b.y);
    r[6] = (short)f2bf(b.z); r[7] = (short)f2bf(b.w);
    return r;
}

// ---------------------------------------------------------------------------
// Prep: bf16 mirrors of seq/pe/ce; pack W f32 [200][2304] -> bf16 tiled with
// 16 n-tiles (rows >= 200 zero): Wp[((t*288+kb8)*16+n)*8+j] = W[t*16+n][kb8*8+j]
// ---------------------------------------------------------------------------
__global__ void prep_kernel(const float* __restrict__ seq,
                            const float* __restrict__ pe,
                            const float* __restrict__ ce,
                            const float* __restrict__ W,
                            unsigned short* __restrict__ ws) {
    int g = blockIdx.x * 256 + threadIdx.x;
    if (g < NSEQ_G) {
        const float* p = seq + (size_t)g * 8;
        *(short8*)(ws + SEQB_OFF + (size_t)g * 8) =
            pack8(*(const f32x4*)p, *(const f32x4*)(p + 4));
        return;
    }
    g -= NSEQ_G;
    if (g < NPE_G) {
        const float* p = pe + (size_t)g * 8;
        *(short8*)(ws + PEB_OFF + (size_t)g * 8) =
            pack8(*(const f32x4*)p, *(const f32x4*)(p + 4));
        return;
    }
    g -= NPE_G;
    if (g < NCE_G) {
        const float* p = ce + (size_t)g * 8;
        *(short8*)(ws + CEB_OFF + (size_t)g * 8) =
            pack8(*(const f32x4*)p, *(const f32x4*)(p + 4));
        return;
    }
    g -= NCE_G;
    if (g < NW16_G) {
        int n   = g & 15;
        int kb8 = (g >> 4) % 288;
        int t   = g / (288 * 16);
        int row = t * 16 + n;
        int col = kb8 * 8;
        f32x4 a = {0.f, 0.f, 0.f, 0.f}, b = {0.f, 0.f, 0.f, 0.f};
        if (row < 200) {
            const float* p = W + (size_t)row * 2304 + col;
            a = *(const f32x4*)p;
            b = *(const f32x4*)(p + 4);
        }
        *(short8*)(ws + WP_OFF + (size_t)g * 8) = pack8(a, b);
    }
}

// ---------------------------------------------------------------------------
// GEMM: grid 256 x 512 thr. Block b -> rows [64b, 64b+64), batch i = b>>2.
// ---------------------------------------------------------------------------
__global__ __launch_bounds__(512) void gemm4_kernel(
    const unsigned short* __restrict__ ws,
    const float* __restrict__ bias,
    const int*   __restrict__ head,
    const int*   __restrict__ frame,
    const int*   __restrict__ pos,
    float* __restrict__ out)
{
    const unsigned short* seqb = ws + SEQB_OFF;
    const unsigned short* peb  = ws + PEB_OFF;
    const unsigned short* ceb  = ws + CEB_OFF;
    const unsigned short* Wp   = ws + WP_OFF;

    const int tid  = threadIdx.x;
    const int wave = tid >> 6;
    const int lane = tid & 63;
    const int n16  = lane & 15;
    const int quad = lane >> 4;
    const int p    = wave & 1;   // m-pair select
    const int q    = wave >> 1;  // tile group: {q, q+4, q+8, q+12}

    const int i       = blockIdx.x >> 2;
    const int pos_i   = pos[i];
    const int frame_i = frame[i];

    // A fragment base pointers per segment per m-frag
    const unsigned short* ab[3][2];
#pragma unroll
    for (int mf = 0; mf < 2; ++mf) {
        const int mrow = blockIdx.x * 64 + (2 * p + mf) * 16 + n16;
        const int j    = mrow & 255;
        const int hi   = head[mrow];
        const int rel  = j - pos_i + 256;               // [1, 511]
        const int cls  = (j == pos_i) ? frame_i : 0;
        ab[0][mf] = seqb + ((size_t)i * 256 + (size_t)hi) * 768 + quad * 8;
        ab[1][mf] = peb + (size_t)rel * 768 + quad * 8;
        ab[2][mf] = ceb + (size_t)cls * 768 + quad * 8;
    }

    // B fragment base pointers for the 4 owned tiles
    const unsigned short* bp[4];
#pragma unroll
    for (int u = 0; u < 4; ++u)
        bp[u] = Wp + (size_t)(q + 4 * u) * TILE_STRIDE +
                (size_t)quad * 128 + (size_t)n16 * 8;

    f32x4 acc[2][4];
#pragma unroll
    for (int u = 0; u < 4; ++u) {
        const int col = (q + 4 * u) * 16 + n16;
        const float bv = (col < 200) ? bias[col] : 0.0f;
        acc[0][u] = (f32x4){bv, bv, bv, bv};
        acc[1][u] = (f32x4){bv, bv, bv, bv};
    }

    short8 abuf[3][2];
    short8 bbuf[3][4];

#pragma unroll
    for (int sg = 0; sg < 3; ++sg) {
        const unsigned short* a0 = ab[sg][0];
        const unsigned short* a1 = ab[sg][1];
        const unsigned short* b0 = bp[0] + (size_t)sg * 12288;
        const unsigned short* b1 = bp[1] + (size_t)sg * 12288;
        const unsigned short* b2 = bp[2] + (size_t)sg * 12288;
        const unsigned short* b3 = bp[3] + (size_t)sg * 12288;

        // prologue: stages 0 and 1 into buffers 0 and 1
#pragma unroll
        for (int s = 0; s < 2; ++s) {
            abuf[s][0] = *(const short8*)(a0 + s * 32);
            abuf[s][1] = *(const short8*)(a1 + s * 32);
            bbuf[s][0] = *(const short8*)(b0 + s * 512);
            bbuf[s][1] = *(const short8*)(b1 + s * 512);
            bbuf[s][2] = *(const short8*)(b2 + s * 512);
            bbuf[s][3] = *(const short8*)(b3 + s * 512);
        }

#pragma unroll
        for (int kk = 0; kk < 24; ++kk) {
            const int kp = (kk + 2 <= 23) ? (kk + 2) : 23;  // compile-time clamp
            const int pb = (kk + 2) % 3;                     // prefetch buffer
            const int cb = kk % 3;                           // compute buffer
            // prefetch stage kk+2 (buffer pb was consumed at iter kk-1)
            abuf[pb][0] = *(const short8*)(a0 + kp * 32);
            abuf[pb][1] = *(const short8*)(a1 + kp * 32);
            bbuf[pb][0] = *(const short8*)(b0 + kp * 512);
            bbuf[pb][1] = *(const short8*)(b1 + kp * 512);
            bbuf[pb][2] = *(const short8*)(b2 + kp * 512);
            bbuf[pb][3] = *(const short8*)(b3 + kp * 512);
            // compute stage kk
#pragma unroll
            for (int u = 0; u < 4; ++u) {
                acc[0][u] = __builtin_amdgcn_mfma_f32_16x16x32_bf16(
                    abuf[cb][0], bbuf[cb][u], acc[0][u], 0, 0, 0);
                acc[1][u] = __builtin_amdgcn_mfma_f32_16x16x32_bf16(
                    abuf[cb][1], bbuf[cb][u], acc[1][u], 0, 0, 0);
            }
        }
    }

    // epilogue: C/D layout col = lane&15, row = quad*4 + r
#pragma unroll
    for (int mf = 0; mf < 2; ++mf) {
        const int rbase = blockIdx.x * 64 + (2 * p + mf) * 16 + quad * 4;
#pragma unroll
        for (int u = 0; u < 4; ++u) {
            const int col = (q + 4 * u) * 16 + n16;
            if (col < 200) {
#pragma unroll
                for (int r = 0; r < 4; ++r)
                    out[(size_t)(rbase + r) * 200 + col] = acc[mf][u][r];
            }
        }
    }
}

// ---------------------------------------------------------------------------
// Fallback (no workspace): slow but correct, f32 W converted inline.
// ---------------------------------------------------------------------------
__global__ __launch_bounds__(256) void gemm_fallback(
    const float* __restrict__ seq, const float* __restrict__ pe,
    const float* __restrict__ ce, const float* __restrict__ Wf,
    const float* __restrict__ bias, const int* __restrict__ head,
    const int* __restrict__ frame, const int* __restrict__ pos,
    float* __restrict__ out)
{
    const int tid  = threadIdx.x;
    const int wave = tid >> 6;
    const int lane = tid & 63;
    const int n16  = lane & 15;
    const int quad = lane >> 4;

    const int mrow  = blockIdx.x * 16 + n16;
    const int i     = mrow >> 8;
    const int j     = mrow & 255;
    const int pos_i = pos[i];
    const int hi    = head[mrow];
    const int rel   = j - pos_i + 256;
    const int cls   = (j == pos_i) ? frame[i] : 0;

    const float* segs[3];
    segs[0] = seq + ((size_t)i * 256 + (size_t)hi) * 768 + quad * 8;
    segs[1] = pe + (size_t)rel * 768 + quad * 8;
    segs[2] = ce + (size_t)cls * 768 + quad * 8;

    const int ntl = (wave == 0) ? 4 : 3;
    f32x4 acc[4];
#pragma unroll
    for (int u = 0; u < 4; ++u) {
        const int t = wave + 4 * u;
        const int col = t * 16 + n16;
        const float bv = (t < 13 && col < 200) ? bias[col] : 0.0f;
        acc[u] = (f32x4){bv, bv, bv, bv};
    }

    for (int s = 0; s < 3; ++s) {
        const float* ap = segs[s];
#pragma unroll 2
        for (int kk = 0; kk < 768; kk += 32) {
            short8 afr = pack8(*(const f32x4*)(ap + kk), *(const f32x4*)(ap + kk + 4));
#pragma unroll
            for (int u = 0; u < 4; ++u) {
                if (u < ntl) {
                    const int t = wave + 4 * u;
                    const int row = t * 16 + n16;
                    short8 bfr = {0, 0, 0, 0, 0, 0, 0, 0};
                    if (row < 200) {
                        const float* qp = Wf + (size_t)row * 2304 + s * 768 + kk + quad * 8;
                        bfr = pack8(*(const f32x4*)qp, *(const f32x4*)(qp + 4));
                    }
                    acc[u] = __builtin_amdgcn_mfma_f32_16x16x32_bf16(afr, bfr, acc[u], 0, 0, 0);
                }
            }
        }
    }

    const int rbase = blockIdx.x * 16 + quad * 4;
#pragma unroll
    for (int u = 0; u < 4; ++u) {
        const int t = wave + 4 * u;
        if (t < 13) {
            const int col = t * 16 + n16;
            if (col < 200) {
#pragma unroll
                for (int r = 0; r < 4; ++r)
                    out[(size_t)(rbase + r) * 200 + col] = acc[u][r];
            }
        }
    }
}

// ---------------------------------------------------------------------------
extern "C" void kernel_launch(void* const* d_in, const int* in_sizes, int n_in,
                              void* d_out, int out_size, void* d_ws, size_t ws_size,
                              hipStream_t stream) {
    const float* seq  = (const float*)d_in[0];
    const float* pe   = (const float*)d_in[1];
    const float* ce   = (const float*)d_in[2];
    const float* W    = (const float*)d_in[3];
    const float* bias = (const float*)d_in[4];
    const int* head   = (const int*)d_in[5];
    const int* frame  = (const int*)d_in[6];
    const int* pos    = (const int*)d_in[7];
    float* out = (float*)d_out;

    if (d_ws != nullptr && ws_size >= WS_NEED) {
        unsigned short* ws = (unsigned short*)d_ws;
        const int total_g = NSEQ_G + NPE_G + NCE_G + NW16_G;   // 1,715,136
        prep_kernel<<<(total_g + 255) / 256, 256, 0, stream>>>(seq, pe, ce, W, ws);
        gemm4_kernel<<<256, 512, 0, stream>>>(ws, bias, head, frame, pos, out);
    } else {
        gemm_fallback<<<1024, 256, 0, stream>>>(seq, pe, ce, W, bias, head,
                                                frame, pos, out);
    }
}

// Round 6
// 131.574 us; speedup vs baseline: 1.3756x; 1.2234x over previous
//
#include <hip/hip_runtime.h>
#include <stdint.h>

// Bert4Argument: out[b,l,c] = sum_f feat[b,l,f] * W[c,f] + b[c]
// feat = [ seq[i, head[i,l], :] | pos_emb[l-pos[i]+256, :] | class_emb[(l==pos[i])?frame[i]:0, :] ]
// B=64, L=256, D=768 -> M=16384, K=2304, N=200 (padded to 16 tiles of 16)
//
// R6: m97-style global_load_lds -> barrier -> ds_read -> MFMA. The compiler
// refuses register pipelines (R4/R5: VGPR stays ~60, loads serialize at full
// L2/L3 latency); LDS-DMA + cross-block TLP is the structure it respects.
//  - grid 512 = 256 m-blocks (64 rows) x 2 n-halves (8 tiles of 16 cols).
//  - block 512 thr / 8 waves, ONE 24 KB LDS buffer -> 2 blocks/CU resident;
//    one block computes while the other waits its barrier drain.
//  - per 64-K chunk per wave: 3 DMAs (1 A, 2 B), barrier, 8 ds_read_b128 +
//    8 MFMAs, barrier. Branchless.

typedef __attribute__((ext_vector_type(8))) short short8;
typedef __attribute__((ext_vector_type(4))) float f32x4;

#define AS1 __attribute__((address_space(1)))
#define AS3 __attribute__((address_space(3)))

#define NSEQ_G 1572864   // 64*256*768/8
#define NPE_G  49248     // 513*768/8
#define NCE_G  19296     // 201*768/8
#define NW16_G 73728     // 16*288*16
#define SEQB_OFF 0
#define PEB_OFF  12582912
#define CEB_OFF  (PEB_OFF + 393984)     // 12,976,896
#define WP_OFF   (CEB_OFF + 154368)     // 13,131,264
#define WS_ELEMS (WP_OFF + 589824)      // 13,721,088
#define WS_NEED  ((size_t)WS_ELEMS * 2) // 27,442,176 B
#define TILE_STRIDE 36864               // 288*16*8 elems per packed n-tile

__device__ __forceinline__ unsigned short f2bf(float f) {
    union { float f; unsigned int u; } v; v.f = f;
    unsigned int u = v.u;
    return (unsigned short)((u + 0x7fffu + ((u >> 16) & 1u)) >> 16);
}

__device__ __forceinline__ short8 pack8(f32x4 a, f32x4 b) {
    short8 r;
    r[0] = (short)f2bf(a.x); r[1] = (short)f2bf(a.y);
    r[2] = (short)f2bf(a.z); r[3] = (short)f2bf(a.w);
    r[4] = (short)f2bf(b.x); r[5] = (short)f2bf(b.y);
    r[6] = (short)f2bf(b.z); r[7] = (short)f2bf(b.w);
    return r;
}

__device__ __forceinline__ void dma16(const unsigned short* g, AS3 unsigned short* l) {
    __builtin_amdgcn_global_load_lds((AS1 const unsigned int*)g,
                                     (AS3 unsigned int*)l, 16, 0, 0);
}

// ---------------------------------------------------------------------------
// Prep: bf16 mirrors of seq/pe/ce; pack W f32 [200][2304] -> bf16 tiled with
// 16 n-tiles (rows >= 200 zero): Wp[((t*288+kb8)*16+n)*8+j] = W[t*16+n][kb8*8+j]
// ---------------------------------------------------------------------------
__global__ void prep_kernel(const float* __restrict__ seq,
                            const float* __restrict__ pe,
                            const float* __restrict__ ce,
                            const float* __restrict__ W,
                            unsigned short* __restrict__ ws) {
    int g = blockIdx.x * 256 + threadIdx.x;
    if (g < NSEQ_G) {
        const float* p = seq + (size_t)g * 8;
        *(short8*)(ws + SEQB_OFF + (size_t)g * 8) =
            pack8(*(const f32x4*)p, *(const f32x4*)(p + 4));
        return;
    }
    g -= NSEQ_G;
    if (g < NPE_G) {
        const float* p = pe + (size_t)g * 8;
        *(short8*)(ws + PEB_OFF + (size_t)g * 8) =
            pack8(*(const f32x4*)p, *(const f32x4*)(p + 4));
        return;
    }
    g -= NPE_G;
    if (g < NCE_G) {
        const float* p = ce + (size_t)g * 8;
        *(short8*)(ws + CEB_OFF + (size_t)g * 8) =
            pack8(*(const f32x4*)p, *(const f32x4*)(p + 4));
        return;
    }
    g -= NCE_G;
    if (g < NW16_G) {
        int n   = g & 15;
        int kb8 = (g >> 4) % 288;
        int t   = g / (288 * 16);
        int row = t * 16 + n;
        int col = kb8 * 8;
        f32x4 a = {0.f, 0.f, 0.f, 0.f}, b = {0.f, 0.f, 0.f, 0.f};
        if (row < 200) {
            const float* p = W + (size_t)row * 2304 + col;
            a = *(const f32x4*)p;
            b = *(const f32x4*)(p + 4);
        }
        *(short8*)(ws + WP_OFF + (size_t)g * 8) = pack8(a, b);
    }
}

// ---------------------------------------------------------------------------
// GEMM: grid 512 x 512 thr. mblk = blockIdx&255 -> rows [64*mblk, +64),
// h = blockIdx>>8 -> n-tiles [8h, 8h+8). Batch i = mblk>>2.
// LDS (24 KB): A frag-ordered [ (mf*2+ks)*64 + lane ]*8  (4096 shorts)
//              B per local tile [ w*1024 + ks*512 + lane*8 ] (8192 shorts)
// ---------------------------------------------------------------------------
__global__ __launch_bounds__(512) void gemm5_kernel(
    const unsigned short* __restrict__ ws,
    const float* __restrict__ bias,
    const int*   __restrict__ head,
    const int*   __restrict__ frame,
    const int*   __restrict__ pos,
    float* __restrict__ out)
{
    __shared__ unsigned short lds[4096 + 8192];   // 24 KB

    const unsigned short* seqb = ws + SEQB_OFF;
    const unsigned short* peb  = ws + PEB_OFF;
    const unsigned short* ceb  = ws + CEB_OFF;
    const unsigned short* Wp   = ws + WP_OFF;

    const int tid  = threadIdx.x;
    const int wave = tid >> 6;
    const int lane = tid & 63;
    const int n16  = lane & 15;
    const int quad = lane >> 4;

    const int mblk = blockIdx.x & 255;
    const int h    = blockIdx.x >> 8;

    const int i       = mblk >> 2;
    const int pos_i   = pos[i];
    const int frame_i = frame[i];

    // ---- A staging: wave stages fragment (mf = wave&3, ks = wave>>2) ----
    const int smf = wave & 3;
    const int sks = wave >> 2;
    const int srow = mblk * 64 + smf * 16 + n16;
    const unsigned short* aSt[3];
    {
        const int sj   = srow & 255;
        const int shi  = head[srow];
        const int srel = sj - pos_i + 256;                 // [1, 511]
        const int scls = (sj == pos_i) ? frame_i : 0;
        const int loff = sks * 32 + quad * 8;              // per-lane k offset
        aSt[0] = seqb + ((size_t)i * 256 + (size_t)shi) * 768 + loff;
        aSt[1] = peb + (size_t)srel * 768 + loff;
        aSt[2] = ceb + (size_t)scls * 768 + loff;
    }
    AS3 unsigned short* aDst =
        (AS3 unsigned short*)lds + ((smf * 2 + sks) * 64 + lane) * 8;

    // ---- B staging: wave stages local tile `wave` (global tile h*8+wave) ----
    const unsigned short* bSt = Wp + (size_t)(h * 8 + wave) * TILE_STRIDE + lane * 8;
    AS3 unsigned short* bDst =
        (AS3 unsigned short*)lds + 4096 + wave * 1024 + lane * 8;

    // ---- compute partition: p = wave&1 -> m-frags {2p,2p+1};
    //      q = wave>>1 -> local tiles {q, q+4} ----
    const int p = wave & 1;
    const int q = wave >> 1;

    const unsigned short* aRd[2][2];
    const unsigned short* bRd[2][2];
#pragma unroll
    for (int f = 0; f < 2; ++f)
#pragma unroll
        for (int ks = 0; ks < 2; ++ks)
            aRd[f][ks] = lds + (((2 * p + f) * 2 + ks) * 64 + lane) * 8;
#pragma unroll
    for (int u = 0; u < 2; ++u)
#pragma unroll
        for (int ks = 0; ks < 2; ++ks)
            bRd[u][ks] = lds + 4096 + (q + 4 * u) * 1024 + ks * 512 + lane * 8;

    f32x4 acc[2][2];
#pragma unroll
    for (int u = 0; u < 2; ++u) {
        const int col = (h * 8 + q + 4 * u) * 16 + n16;
        const float bv = (col < 200) ? bias[col] : 0.0f;
        acc[0][u] = (f32x4){bv, bv, bv, bv};
        acc[1][u] = (f32x4){bv, bv, bv, bv};
    }

#pragma unroll
    for (int sg = 0; sg < 3; ++sg) {
        const unsigned short* aSrc = aSt[sg];
        const unsigned short* bSrc = bSt + (size_t)sg * 12288;  // 12 chunks * 1024
        for (int cc = 0; cc < 12; ++cc) {
            // stage chunk (64 k-values)
            dma16(aSrc + cc * 64, aDst);
            dma16(bSrc + cc * 1024, bDst);
            dma16(bSrc + cc * 1024 + 512, bDst + 512);
            __syncthreads();
            // compute
#pragma unroll
            for (int ks = 0; ks < 2; ++ks) {
                short8 a0 = *(const short8*)aRd[0][ks];
                short8 a1 = *(const short8*)aRd[1][ks];
#pragma unroll
                for (int u = 0; u < 2; ++u) {
                    short8 bf = *(const short8*)bRd[u][ks];
                    acc[0][u] = __builtin_amdgcn_mfma_f32_16x16x32_bf16(a0, bf, acc[0][u], 0, 0, 0);
                    acc[1][u] = __builtin_amdgcn_mfma_f32_16x16x32_bf16(a1, bf, acc[1][u], 0, 0, 0);
                }
            }
            __syncthreads();
        }
    }

    // epilogue: C/D layout col = lane&15, row = quad*4 + r
#pragma unroll
    for (int f = 0; f < 2; ++f) {
        const int rbase = mblk * 64 + (2 * p + f) * 16 + quad * 4;
#pragma unroll
        for (int u = 0; u < 2; ++u) {
            const int col = (h * 8 + q + 4 * u) * 16 + n16;
            if (col < 200) {
#pragma unroll
                for (int r = 0; r < 4; ++r)
                    out[(size_t)(rbase + r) * 200 + col] = acc[f][u][r];
            }
        }
    }
}

// ---------------------------------------------------------------------------
// Fallback (no workspace): slow but correct, f32 W converted inline.
// ---------------------------------------------------------------------------
__global__ __launch_bounds__(256) void gemm_fallback(
    const float* __restrict__ seq, const float* __restrict__ pe,
    const float* __restrict__ ce, const float* __restrict__ Wf,
    const float* __restrict__ bias, const int* __restrict__ head,
    const int* __restrict__ frame, const int* __restrict__ pos,
    float* __restrict__ out)
{
    const int tid  = threadIdx.x;
    const int wave = tid >> 6;
    const int lane = tid & 63;
    const int n16  = lane & 15;
    const int quad = lane >> 4;

    const int mrow  = blockIdx.x * 16 + n16;
    const int i     = mrow >> 8;
    const int j     = mrow & 255;
    const int pos_i = pos[i];
    const int hi    = head[mrow];
    const int rel   = j - pos_i + 256;
    const int cls   = (j == pos_i) ? frame[i] : 0;

    const float* segs[3];
    segs[0] = seq + ((size_t)i * 256 + (size_t)hi) * 768 + quad * 8;
    segs[1] = pe + (size_t)rel * 768 + quad * 8;
    segs[2] = ce + (size_t)cls * 768 + quad * 8;

    const int ntl = (wave == 0) ? 4 : 3;
    f32x4 acc[4];
#pragma unroll
    for (int u = 0; u < 4; ++u) {
        const int t = wave + 4 * u;
        const int col = t * 16 + n16;
        const float bv = (t < 13 && col < 200) ? bias[col] : 0.0f;
        acc[u] = (f32x4){bv, bv, bv, bv};
    }

    for (int s = 0; s < 3; ++s) {
        const float* ap = segs[s];
#pragma unroll 2
        for (int kk = 0; kk < 768; kk += 32) {
            short8 afr = pack8(*(const f32x4*)(ap + kk), *(const f32x4*)(ap + kk + 4));
#pragma unroll
            for (int u = 0; u < 4; ++u) {
                if (u < ntl) {
                    const int t = wave + 4 * u;
                    const int row = t * 16 + n16;
                    short8 bfr = {0, 0, 0, 0, 0, 0, 0, 0};
                    if (row < 200) {
                        const float* qp = Wf + (size_t)row * 2304 + s * 768 + kk + quad * 8;
                        bfr = pack8(*(const f32x4*)qp, *(const f32x4*)(qp + 4));
                    }
                    acc[u] = __builtin_amdgcn_mfma_f32_16x16x32_bf16(afr, bfr, acc[u], 0, 0, 0);
                }
            }
        }
    }

    const int rbase = blockIdx.x * 16 + quad * 4;
#pragma unroll
    for (int u = 0; u < 4; ++u) {
        const int t = wave + 4 * u;
        if (t < 13) {
            const int col = t * 16 + n16;
            if (col < 200) {
#pragma unroll
                for (int r = 0; r < 4; ++r)
                    out[(size_t)(rbase + r) * 200 + col] = acc[u][r];
            }
        }
    }
}

// ---------------------------------------------------------------------------
extern "C" void kernel_launch(void* const* d_in, const int* in_sizes, int n_in,
                              void* d_out, int out_size, void* d_ws, size_t ws_size,
                              hipStream_t stream) {
    const float* seq  = (const float*)d_in[0];
    const float* pe   = (const float*)d_in[1];
    const float* ce   = (const float*)d_in[2];
    const float* W    = (const float*)d_in[3];
    const float* bias = (const float*)d_in[4];
    const int* head   = (const int*)d_in[5];
    const int* frame  = (const int*)d_in[6];
    const int* pos    = (const int*)d_in[7];
    float* out = (float*)d_out;

    if (d_ws != nullptr && ws_size >= WS_NEED) {
        unsigned short* ws = (unsigned short*)d_ws;
        const int total_g = NSEQ_G + NPE_G + NCE_G + NW16_G;   // 1,715,136
        prep_kernel<<<(total_g + 255) / 256, 256, 0, stream>>>(seq, pe, ce, W, ws);
        gemm5_kernel<<<512, 512, 0, stream>>>(ws, bias, head, frame, pos, out);
    } else {
        gemm_fallback<<<1024, 256, 0, stream>>>(seq, pe, ce, W, bias, head,
                                                frame, pos, out);
    }
}

// Round 7
// 129.705 us; speedup vs baseline: 1.3955x; 1.0144x over previous
//
#include <hip/hip_runtime.h>
#include <stdint.h>

// Bert4Argument: out[b,l,c] = sum_f feat[b,l,f] * W[c,f] + b[c]
// feat = [ seq[i, head[i,l], :] | pos_emb[l-pos[i]+256, :] | class_emb[(l==pos[i])?frame[i]:0, :] ]
// B=64, L=256, D=768 -> M=16384, K=2304, N=200 (padded to 16 tiles of 16)
//
// R7: R6 structure (global_load_lds -> barrier -> ds_read -> MFMA, 2 blocks/CU)
// with K-chunk doubled 64 -> 128: barrier drains halve (36 -> 18 per block),
// DMA and LDS-read totals unchanged. LDS 24 -> 48 KB (A 16 KB frag-ordered,
// B 32 KB), still 2 blocks/CU (96 KB of 160, 1024 thr of 2048).

typedef __attribute__((ext_vector_type(8))) short short8;
typedef __attribute__((ext_vector_type(4))) float f32x4;

#define AS1 __attribute__((address_space(1)))
#define AS3 __attribute__((address_space(3)))

#define NSEQ_G 1572864   // 64*256*768/8
#define NPE_G  49248     // 513*768/8
#define NCE_G  19296     // 201*768/8
#define NW16_G 73728     // 16*288*16
#define SEQB_OFF 0
#define PEB_OFF  12582912
#define CEB_OFF  (PEB_OFF + 393984)     // 12,976,896
#define WP_OFF   (CEB_OFF + 154368)     // 13,131,264
#define WS_ELEMS (WP_OFF + 589824)      // 13,721,088
#define WS_NEED  ((size_t)WS_ELEMS * 2) // 27,442,176 B
#define TILE_STRIDE 36864               // 288*16*8 elems per packed n-tile

__device__ __forceinline__ unsigned short f2bf(float f) {
    union { float f; unsigned int u; } v; v.f = f;
    unsigned int u = v.u;
    return (unsigned short)((u + 0x7fffu + ((u >> 16) & 1u)) >> 16);
}

__device__ __forceinline__ short8 pack8(f32x4 a, f32x4 b) {
    short8 r;
    r[0] = (short)f2bf(a.x); r[1] = (short)f2bf(a.y);
    r[2] = (short)f2bf(a.z); r[3] = (short)f2bf(a.w);
    r[4] = (short)f2bf(b.x); r[5] = (short)f2bf(b.y);
    r[6] = (short)f2bf(b.z); r[7] = (short)f2bf(b.w);
    return r;
}

__device__ __forceinline__ void dma16(const unsigned short* g, AS3 unsigned short* l) {
    __builtin_amdgcn_global_load_lds((AS1 const unsigned int*)g,
                                     (AS3 unsigned int*)l, 16, 0, 0);
}

// ---------------------------------------------------------------------------
// Prep: bf16 mirrors of seq/pe/ce; pack W f32 [200][2304] -> bf16 tiled with
// 16 n-tiles (rows >= 200 zero): Wp[((t*288+kb8)*16+n)*8+j] = W[t*16+n][kb8*8+j]
// ---------------------------------------------------------------------------
__global__ void prep_kernel(const float* __restrict__ seq,
                            const float* __restrict__ pe,
                            const float* __restrict__ ce,
                            const float* __restrict__ W,
                            unsigned short* __restrict__ ws) {
    int g = blockIdx.x * 256 + threadIdx.x;
    if (g < NSEQ_G) {
        const float* p = seq + (size_t)g * 8;
        *(short8*)(ws + SEQB_OFF + (size_t)g * 8) =
            pack8(*(const f32x4*)p, *(const f32x4*)(p + 4));
        return;
    }
    g -= NSEQ_G;
    if (g < NPE_G) {
        const float* p = pe + (size_t)g * 8;
        *(short8*)(ws + PEB_OFF + (size_t)g * 8) =
            pack8(*(const f32x4*)p, *(const f32x4*)(p + 4));
        return;
    }
    g -= NPE_G;
    if (g < NCE_G) {
        const float* p = ce + (size_t)g * 8;
        *(short8*)(ws + CEB_OFF + (size_t)g * 8) =
            pack8(*(const f32x4*)p, *(const f32x4*)(p + 4));
        return;
    }
    g -= NCE_G;
    if (g < NW16_G) {
        int n   = g & 15;
        int kb8 = (g >> 4) % 288;
        int t   = g / (288 * 16);
        int row = t * 16 + n;
        int col = kb8 * 8;
        f32x4 a = {0.f, 0.f, 0.f, 0.f}, b = {0.f, 0.f, 0.f, 0.f};
        if (row < 200) {
            const float* p = W + (size_t)row * 2304 + col;
            a = *(const f32x4*)p;
            b = *(const f32x4*)(p + 4);
        }
        *(short8*)(ws + WP_OFF + (size_t)g * 8) = pack8(a, b);
    }
}

// ---------------------------------------------------------------------------
// GEMM: grid 512 x 512 thr. mblk = blockIdx&255 -> rows [64*mblk, +64),
// h = blockIdx>>8 -> n-tiles [8h, 8h+8). Batch i = mblk>>2. K-chunk = 128.
// LDS (48 KB):
//   A: 16 slabs (fm 0..3, ks 0..3), slab = 64 lanes x 8 bf16 = 1 KB.
//      addr = ((fm*4 + ks)*64 + lane)*8 shorts.
//   B: 8 local tiles x 2048 shorts (16 kb8-blocks x 16 n x 8), at +8192.
//      addr = 8192 + t*2048 + (ks*4+quad)*128 + n16*8.
// Staging per wave per chunk: 2 A dma16 (fm=w&3, ks = (w>>2)*2 + {0,1}),
// 4 B dma16 (tile w). Compute: wave p=w&1 -> m-frags {2p,2p+1},
// q=w>>1 -> local tiles {q,q+4}; 4 ks x (2 A + 2 B ds_read_b128, 4 MFMA).
// ---------------------------------------------------------------------------
__global__ __launch_bounds__(512) void gemm6_kernel(
    const unsigned short* __restrict__ ws,
    const float* __restrict__ bias,
    const int*   __restrict__ head,
    const int*   __restrict__ frame,
    const int*   __restrict__ pos,
    float* __restrict__ out)
{
    __shared__ unsigned short lds[8192 + 16384];   // 48 KB

    const unsigned short* seqb = ws + SEQB_OFF;
    const unsigned short* peb  = ws + PEB_OFF;
    const unsigned short* ceb  = ws + CEB_OFF;
    const unsigned short* Wp   = ws + WP_OFF;

    const int tid  = threadIdx.x;
    const int wave = tid >> 6;
    const int lane = tid & 63;
    const int n16  = lane & 15;
    const int quad = lane >> 4;

    const int mblk = blockIdx.x & 255;
    const int h    = blockIdx.x >> 8;

    const int i       = mblk >> 2;
    const int pos_i   = pos[i];
    const int frame_i = frame[i];

    // ---- A staging: wave stages fragment fm = wave&3, ks-pair = wave>>2 ----
    const int smf = wave & 3;
    const int skb = (wave >> 2) * 2;            // ks base: 0 or 2
    const int srow = mblk * 64 + smf * 16 + n16;
    const unsigned short* aSt[3];
    {
        const int sj   = srow & 255;
        const int shi  = head[srow];
        const int srel = sj - pos_i + 256;                 // [1, 511]
        const int scls = (sj == pos_i) ? frame_i : 0;
        const int loff = quad * 8;
        aSt[0] = seqb + ((size_t)i * 256 + (size_t)shi) * 768 + loff;
        aSt[1] = peb + (size_t)srel * 768 + loff;
        aSt[2] = ceb + (size_t)scls * 768 + loff;
    }
    AS3 unsigned short* aDst0 =
        (AS3 unsigned short*)lds + ((smf * 4 + skb) * 64 + lane) * 8;
    AS3 unsigned short* aDst1 = aDst0 + 512;

    // ---- B staging: wave stages local tile `wave` (global tile h*8+wave) ----
    const unsigned short* bSt = Wp + (size_t)(h * 8 + wave) * TILE_STRIDE + lane * 8;
    AS3 unsigned short* bDst =
        (AS3 unsigned short*)lds + 8192 + wave * 2048 + lane * 8;

    // ---- compute partition ----
    const int p = wave & 1;
    const int q = wave >> 1;

    const unsigned short* aRd[2];   // + ks*512
    const unsigned short* bRd[2];   // + ks*512
#pragma unroll
    for (int f = 0; f < 2; ++f)
        aRd[f] = lds + (2 * p + f) * 2048 + lane * 8;
#pragma unroll
    for (int u = 0; u < 2; ++u)
        bRd[u] = lds + 8192 + (q + 4 * u) * 2048 + quad * 128 + n16 * 8;

    f32x4 acc[2][2];
#pragma unroll
    for (int u = 0; u < 2; ++u) {
        const int col = (h * 8 + q + 4 * u) * 16 + n16;
        const float bv = (col < 200) ? bias[col] : 0.0f;
        acc[0][u] = (f32x4){bv, bv, bv, bv};
        acc[1][u] = (f32x4){bv, bv, bv, bv};
    }

#pragma unroll
    for (int sg = 0; sg < 3; ++sg) {
        const unsigned short* aSrc = aSt[sg];
        const unsigned short* bSrc = bSt + (size_t)sg * 12288;  // 6 chunks * 2048
        for (int cc = 0; cc < 6; ++cc) {
            // stage chunk (128 k-values): 2 A + 4 B dma16 per wave
            dma16(aSrc + cc * 128 + skb * 32,      aDst0);
            dma16(aSrc + cc * 128 + skb * 32 + 32, aDst1);
            dma16(bSrc + cc * 2048,        bDst);
            dma16(bSrc + cc * 2048 + 512,  bDst + 512);
            dma16(bSrc + cc * 2048 + 1024, bDst + 1024);
            dma16(bSrc + cc * 2048 + 1536, bDst + 1536);
            __syncthreads();
            // compute: 4 ks x (2 A + 2 B reads, 4 MFMA)
#pragma unroll
            for (int ks = 0; ks < 4; ++ks) {
                short8 a0 = *(const short8*)(aRd[0] + ks * 512);
                short8 a1 = *(const short8*)(aRd[1] + ks * 512);
#pragma unroll
                for (int u = 0; u < 2; ++u) {
                    short8 bf = *(const short8*)(bRd[u] + ks * 512);
                    acc[0][u] = __builtin_amdgcn_mfma_f32_16x16x32_bf16(a0, bf, acc[0][u], 0, 0, 0);
                    acc[1][u] = __builtin_amdgcn_mfma_f32_16x16x32_bf16(a1, bf, acc[1][u], 0, 0, 0);
                }
            }
            __syncthreads();
        }
    }

    // epilogue: C/D layout col = lane&15, row = quad*4 + r
#pragma unroll
    for (int f = 0; f < 2; ++f) {
        const int rbase = mblk * 64 + (2 * p + f) * 16 + quad * 4;
#pragma unroll
        for (int u = 0; u < 2; ++u) {
            const int col = (h * 8 + q + 4 * u) * 16 + n16;
            if (col < 200) {
#pragma unroll
                for (int r = 0; r < 4; ++r)
                    out[(size_t)(rbase + r) * 200 + col] = acc[f][u][r];
            }
        }
    }
}

// ---------------------------------------------------------------------------
// Fallback (no workspace): slow but correct, f32 W converted inline.
// ---------------------------------------------------------------------------
__global__ __launch_bounds__(256) void gemm_fallback(
    const float* __restrict__ seq, const float* __restrict__ pe,
    const float* __restrict__ ce, const float* __restrict__ Wf,
    const float* __restrict__ bias, const int* __restrict__ head,
    const int* __restrict__ frame, const int* __restrict__ pos,
    float* __restrict__ out)
{
    const int tid  = threadIdx.x;
    const int wave = tid >> 6;
    const int lane = tid & 63;
    const int n16  = lane & 15;
    const int quad = lane >> 4;

    const int mrow  = blockIdx.x * 16 + n16;
    const int i     = mrow >> 8;
    const int j     = mrow & 255;
    const int pos_i = pos[i];
    const int hi    = head[mrow];
    const int rel   = j - pos_i + 256;
    const int cls   = (j == pos_i) ? frame[i] : 0;

    const float* segs[3];
    segs[0] = seq + ((size_t)i * 256 + (size_t)hi) * 768 + quad * 8;
    segs[1] = pe + (size_t)rel * 768 + quad * 8;
    segs[2] = ce + (size_t)cls * 768 + quad * 8;

    const int ntl = (wave == 0) ? 4 : 3;
    f32x4 acc[4];
#pragma unroll
    for (int u = 0; u < 4; ++u) {
        const int t = wave + 4 * u;
        const int col = t * 16 + n16;
        const float bv = (t < 13 && col < 200) ? bias[col] : 0.0f;
        acc[u] = (f32x4){bv, bv, bv, bv};
    }

    for (int s = 0; s < 3; ++s) {
        const float* ap = segs[s];
#pragma unroll 2
        for (int kk = 0; kk < 768; kk += 32) {
            short8 afr = pack8(*(const f32x4*)(ap + kk), *(const f32x4*)(ap + kk + 4));
#pragma unroll
            for (int u = 0; u < 4; ++u) {
                if (u < ntl) {
                    const int t = wave + 4 * u;
                    const int row = t * 16 + n16;
                    short8 bfr = {0, 0, 0, 0, 0, 0, 0, 0};
                    if (row < 200) {
                        const float* qp = Wf + (size_t)row * 2304 + s * 768 + kk + quad * 8;
                        bfr = pack8(*(const f32x4*)qp, *(const f32x4*)(qp + 4));
                    }
                    acc[u] = __builtin_amdgcn_mfma_f32_16x16x32_bf16(afr, bfr, acc[u], 0, 0, 0);
                }
            }
        }
    }

    const int rbase = blockIdx.x * 16 + quad * 4;
#pragma unroll
    for (int u = 0; u < 4; ++u) {
        const int t = wave + 4 * u;
        if (t < 13) {
            const int col = t * 16 + n16;
            if (col < 200) {
#pragma unroll
                for (int r = 0; r < 4; ++r)
                    out[(size_t)(rbase + r) * 200 + col] = acc[u][r];
            }
        }
    }
}

// ---------------------------------------------------------------------------
extern "C" void kernel_launch(void* const* d_in, const int* in_sizes, int n_in,
                              void* d_out, int out_size, void* d_ws, size_t ws_size,
                              hipStream_t stream) {
    const float* seq  = (const float*)d_in[0];
    const float* pe   = (const float*)d_in[1];
    const float* ce   = (const float*)d_in[2];
    const float* W    = (const float*)d_in[3];
    const float* bias = (const float*)d_in[4];
    const int* head   = (const int*)d_in[5];
    const int* frame  = (const int*)d_in[6];
    const int* pos    = (const int*)d_in[7];
    float* out = (float*)d_out;

    if (d_ws != nullptr && ws_size >= WS_NEED) {
        unsigned short* ws = (unsigned short*)d_ws;
        const int total_g = NSEQ_G + NPE_G + NCE_G + NW16_G;   // 1,715,136
        prep_kernel<<<(total_g + 255) / 256, 256, 0, stream>>>(seq, pe, ce, W, ws);
        gemm6_kernel<<<512, 512, 0, stream>>>(ws, bias, head, frame, pos, out);
    } else {
        gemm_fallback<<<1024, 256, 0, stream>>>(seq, pe, ce, W, bias, head,
                                                frame, pos, out);
    }
}